// Round 10
// baseline (176.272 us; speedup 1.0000x reference)
//
#include <hip/hip_runtime.h>
#include <stdint.h>

// ---------- types ----------
typedef __bf16    bf16x8 __attribute__((ext_vector_type(8)));
typedef float     f32x4  __attribute__((ext_vector_type(4)));
typedef uint32_t  u32x4  __attribute__((ext_vector_type(4)));
typedef uint32_t  u32x2  __attribute__((ext_vector_type(2)));

#define MFMA(a,b,c) __builtin_amdgcn_mfma_f32_16x16x32_bf16((a),(b),(c),0,0,0)

// ---------- persistent device scratch (bf16 internal pipeline) ----------
__device__ __align__(16) uint16_t g_y [8*64*64*256];
__device__ __align__(16) uint16_t g_wpk[393216];

#define WQF 0
#define WKF 65536
#define WVF 131072
#define WCF 196608
#define W1F 262144
#define W2F 294912
#define WPF 327680

static __device__ __forceinline__ float b2f(uint32_t u){ return __builtin_bit_cast(float, u<<16); }
static __device__ __forceinline__ float blo(uint32_t u){ return __builtin_bit_cast(float, u<<16); }
static __device__ __forceinline__ float bhi(uint32_t u){ return __builtin_bit_cast(float, u & 0xffff0000u); }
// native RNE f32->bf16 (same bits as manual RNE round)
static __device__ __forceinline__ uint16_t f2bn(float f){
  return __builtin_bit_cast(uint16_t, (__bf16)f);
}
static __device__ __forceinline__ uint32_t pk2(float x, float y){
  return (uint32_t)f2bn(x) | ((uint32_t)f2bn(y) << 16);
}

// ---------- kernel 0 (fused prep) ----------
// blocks [0,512):   3x3 avgpool, 4 output rows + 64-ch group per block
// blocks [512,1280): weight repack into bf16 B-fragment-major layout
__global__ __launch_bounds__(512) void kprep(const float* __restrict__ x,
    const float* __restrict__ Wqkv, const float* __restrict__ W1,
    const float* __restrict__ W2, const float* __restrict__ Wp){
  int t = threadIdx.x;
  int bid = blockIdx.x;
  if (bid < 512){
    // pool: block = (b, hgroup of 4 rows, chgroup of 64); LDS 63.0 KB -> 2 blocks/CU
    __shared__ __align__(16) uint16_t sm[6*64*82];
    uint32_t* smw = (uint32_t*)sm;
    int b = bid >> 6, rem = bid & 63;
    int hg = rem >> 2, cg = rem & 3;
    int h0 = hg*4, ch = cg*64;
    for (int i=t; i<384; i+=512){
      int base = i*41;
      smw[base+3]  = 0;
      smw[base+36] = 0;
    }
    if (hg==0){
      for (int i=t; i<2624; i+=512) smw[i] = 0;
    }
    if (hg==15){
      for (int i=t; i<2624; i+=512) smw[5*2624 + i] = 0;
    }
    #pragma unroll
    for (int i=0;i<12;i++){
      int id = t + 512*i;
      int w4 = id&15, c = (id>>4)&63, hh = id>>10;
      int gy = h0 - 1 + hh;
      if ((unsigned)gy < 64u){
        f32x4 ld = *(const f32x4*)&x[(((b*256+ch+c)*64+gy)*64) + w4*4];
        int wb = (((hh*64+c)*82 + 8 + w4*4) >> 1);
        smw[wb+0] = pk2(ld[0], ld[1]);
        smw[wb+1] = pk2(ld[2], ld[3]);
      }
    }
    __syncthreads();
    int c = t & 63, wsel = (t >> 6) & 1, py = t >> 7;
    int r0 = ((py+0)*64+c)*82, r1 = ((py+1)*64+c)*82, r2 = ((py+2)*64+c)*82;
    int w0 = wsel*32;
    float csp = b2f(sm[r0+w0+7]) + b2f(sm[r1+w0+7]) + b2f(sm[r2+w0+7]);
    float csc = b2f(sm[r0+w0+8]) + b2f(sm[r1+w0+8]) + b2f(sm[r2+w0+8]);
    uint16_t* dst = g_y + ((b*64 + h0 + py)*64)*256 + ch + c;
    for (int j2=0;j2<32;j2++){
      int w = w0 + j2;
      float csn = b2f(sm[r0+w+9]) + b2f(sm[r1+w+9]) + b2f(sm[r2+w+9]);
      float yv = (csp + csc + csn) * (1.0f/9.0f);
      dst[w*256] = f2bn(yv);
      csp = csc; csc = csn;
    }
  } else {
    int idx = (bid - 512)*512 + t;
    int j = idx & 7, lane = (idx>>3)&63;
    int n16 = lane & 15, q4 = lane>>4;
    float v;
    if (idx < 262144){
      int tt = idx >> 16, l = idx & 65535;
      int s = (l>>9)&7, nt = l>>12;
      v = Wqkv[(4*(nt*16+n16) + tt)*256 + s*32 + q4*8 + j];
    } else if (idx < 294912){
      int l = idx - 262144;
      int s = (l>>9)&7, nt = l>>12;
      v = W1[(nt*16+n16)*256 + s*32 + q4*8 + j];
    } else if (idx < 327680){
      int l = idx - 294912;
      int s = (l>>9)&3, nt = l>>11;
      v = W2[(nt*16+n16)*128 + s*32 + q4*8 + j];
    } else {
      int l = idx - 327680;
      int s = (l>>9)&7, nt = l>>12;
      v = Wp[(nt*16+n16)*256 + s*32 + q4*8 + j];
    }
    g_wpk[idx] = f2bn(v);
  }
}

// ---------- kernel 1: fully fused qkv + attention + chans + gate MLP + proj + out ----------
// tile = 4x8 interior (6x10 halo); LDS 79,808 B -> 2 blocks/CU (4 waves/SIMD)
// r9 structure; ALL row strides chosen == 12 (mod 32) dwords so that 8-row
// b128 access groups tile the 32 banks perfectly (conflict-free):
//   YSTR 280 (140 dw == 12), HSTR 152 (76 dw == 12), MCH stride 280, MHS stride 152.
#define YSTR  280        // Y: 60 halo rows at [0,16800)
#define HSTR  152
#define K2_QS 16800      // Q: 32 x 152
#define K2_KS 21664      // K: 60 x 152
#define K2_VS 30784      // V: 60 x 152  (total 39904 u16 = 79,808 B)
#define MCSTR 280
#define MCH   0          // 32x280 over dead Y rows
#define MHS   8960       // 32x152 over dead Y rows
#define MAO   16800      // 32x266 attn out, over dead Q/K
#define MAOSTR 266
#define MAOT  16800      // 256x36 transposed proj out, overlays dead MAO after W2
#define MTSTR 36
__global__ __launch_bounds__(512,4) void kattn(const float* __restrict__ bqkv,
    const float* __restrict__ b1, const float* __restrict__ b2v,
    const float* __restrict__ bp, float* __restrict__ out){
  __shared__ __align__(16) uint16_t sm[39904];   // 79,808 B
  int t = threadIdx.x;
  int lane = t & 63, wave = t >> 6;
  int n16 = lane & 15, quad = lane >> 4;
  int bid = blockIdx.x;
  int bb = bid >> 7, ty = (bid >> 3) & 15, tx = bid & 7;

  uint32_t opk[2][8];    // packed attention output (waves 0-3)
  uint32_t chp[16];      // packed chans GEMM output (waves 4-7)

  int hrow0 = 10*(n16>>3) + (n16&7) + 11;   // interior row for m = n16
  int hrow1 = hrow0 + 20;                   // interior row for m = 16+n16

  // --- load 6x10 y-halo (zero outside image) ---
  #pragma unroll
  for (int i=0;i<4;i++){
    int id = t + 512*i;
    if (id < 1920){
      int hp = id >> 5, c8 = id & 31;
      int py = hp/10, px = hp - py*10;
      int gy = ty*4 + py - 1, gx = tx*8 + px - 1;
      u32x4 ld = {0,0,0,0};
      if ((unsigned)gy<64u && (unsigned)gx<64u)
        ld = *(const u32x4*)&g_y[((bb*64+gy)*64+gx)*256 + c8*8];
      *(u32x4*)&sm[hp*YSTR + c8*8] = ld;
    }
  }
  __syncthreads();

  #pragma unroll
  for (int hf=0; hf<2; hf++){
    // ---- q GEMM: M=32 interior, N=128 (this half) ----
    {
      int ntg = hf*8 + wave;
      bf16x8 Bq[8];
      #pragma unroll
      for (int s=0;s<8;s++) Bq[s] = *(const bf16x8*)&g_wpk[WQF + ((ntg*8+s)*64+lane)*8];
      float bq = bqkv[4*(ntg*16+n16) + 0];
      int colB = wave*16;
      #pragma unroll
      for (int mt=0; mt<2; mt++){
        f32x4 a = {0.f,0.f,0.f,0.f};
        int hrow = mt ? hrow1 : hrow0;
        #pragma unroll
        for (int s=0;s<8;s++){
          bf16x8 A = *(const bf16x8*)&sm[hrow*YSTR + s*32 + quad*8];
          a = MFMA(A, Bq[s], a);
        }
        #pragma unroll
        for (int r=0;r<4;r++){
          int row = mt*16 + quad*4 + r;
          sm[K2_QS + row*HSTR + colB + n16] = f2bn(a[r] + bq);
        }
      }
    }
    // (no barrier: Q and KV write disjoint LDS, read only Y — proven r8)
    // ---- k & v GEMM (shared A-frags): M=64 (rows >= 60 discarded), N=128 ----
    {
      int ntg = hf*8 + wave;
      bf16x8 Bk[8], Bv[8];
      #pragma unroll
      for (int s=0;s<8;s++){
        Bk[s] = *(const bf16x8*)&g_wpk[WKF + ((ntg*8+s)*64+lane)*8];
        Bv[s] = *(const bf16x8*)&g_wpk[WVF + ((ntg*8+s)*64+lane)*8];
      }
      float bk = bqkv[4*(ntg*16+n16) + 1];
      float bv = bqkv[4*(ntg*16+n16) + 2];
      int colB = wave*16;
      #pragma unroll
      for (int mt=0; mt<4; mt++){
        f32x4 ak = {0.f,0.f,0.f,0.f}, av = {0.f,0.f,0.f,0.f};
        int m = mt*16 + n16;
        int mr = (m < 60) ? m : 59;
        #pragma unroll
        for (int s=0;s<8;s++){
          bf16x8 A = *(const bf16x8*)&sm[mr*YSTR + s*32 + quad*8];
          ak = MFMA(A, Bk[s], ak);
          av = MFMA(A, Bv[s], av);
        }
        #pragma unroll
        for (int r=0;r<4;r++){
          int row = mt*16 + quad*4 + r;
          if (row < 60){
            int py = row/10, px = row - py*10;
            int gy = ty*4 + py - 1, gx = tx*8 + px - 1;
            bool ok = ((unsigned)gy<64u) && ((unsigned)gx<64u);
            sm[K2_KS + row*HSTR + colB + n16] = ok ? f2bn(ak[r] + bk) : (uint16_t)0;
            sm[K2_VS + row*HSTR + colB + n16] = ok ? f2bn(av[r] + bv) : (uint16_t)0;
          }
        }
      }
    }
    __syncthreads();
    if (wave < 4){
      // ---- attention: thread = (pixel, head, ch-half); cross-half dot via shfl_xor ----
      int p = lane & 31, half = lane >> 5;
      int cb = wave*32 + half*16;
      const uint16_t* qp = &sm[K2_QS + p*HSTR + cb];
      u32x4 qa = *(const u32x4*)qp;
      u32x4 qb = *(const u32x4*)(qp+8);
      float qv[16];
      #pragma unroll
      for (int i=0;i<4;i++){
        qv[2*i]    = blo(qa[i]); qv[2*i+1]   = bhi(qa[i]);
        qv[8+2*i]  = blo(qb[i]); qv[8+2*i+1] = bhi(qb[i]);
      }
      int hb = 10*(p>>3) + (p&7) + 11;
      const int off[9] = {-11,-10,-9,-1,0,1,9,10,11};
      float sc[9];
      #pragma unroll
      for (int nb=0;nb<9;nb++){
        const uint16_t* kp = &sm[K2_KS + (hb+off[nb])*HSTR + cb];
        u32x4 ka = *(const u32x4*)kp;
        u32x4 kb = *(const u32x4*)(kp+8);
        float s = 0.f;
        #pragma unroll
        for (int i=0;i<4;i++){
          s += qv[2*i]*blo(ka[i])   + qv[2*i+1]*bhi(ka[i]);
          s += qv[8+2*i]*blo(kb[i]) + qv[8+2*i+1]*bhi(kb[i]);
        }
        s += __shfl_xor(s, 32);            // combine the two 16-ch halves of the head
        sc[nb] = s * 0.17677669529663687f;
      }
      float mx = sc[0];
      #pragma unroll
      for (int nb=1;nb<9;nb++) mx = fmaxf(mx, sc[nb]);
      float l = 0.f;
      #pragma unroll
      for (int nb=0;nb<9;nb++){ sc[nb] = __expf(sc[nb]-mx); l += sc[nb]; }
      float inv = 1.f / l;
      float o[16];
      #pragma unroll
      for (int i=0;i<16;i++) o[i]=0.f;
      #pragma unroll
      for (int nb=0;nb<9;nb++){
        float wgt = sc[nb]*inv;
        const uint16_t* vp = &sm[K2_VS + (hb+off[nb])*HSTR + cb];
        u32x4 va = *(const u32x4*)vp;
        u32x4 vb = *(const u32x4*)(vp+8);
        #pragma unroll
        for (int i=0;i<4;i++){
          o[2*i]    += wgt*blo(va[i]); o[2*i+1]   += wgt*bhi(va[i]);
          o[8+2*i]  += wgt*blo(vb[i]); o[8+2*i+1] += wgt*bhi(vb[i]);
        }
      }
      #pragma unroll
      for (int i=0;i<8;i++) opk[hf][i] = pk2(o[2*i], o[2*i+1]);
    } else if (hf == 0){
      // ---- chans GEMM (concurrent with attn0): A-reads hoisted across jj ----
      f32x4 cc[4][2];
      #pragma unroll
      for (int jj=0;jj<4;jj++){
        cc[jj][0] = f32x4{0.f,0.f,0.f,0.f};
        cc[jj][1] = f32x4{0.f,0.f,0.f,0.f};
      }
      #pragma unroll
      for (int s=0;s<8;s++){
        bf16x8 A0 = *(const bf16x8*)&sm[hrow0*YSTR + s*32 + quad*8];
        bf16x8 A1 = *(const bf16x8*)&sm[hrow1*YSTR + s*32 + quad*8];
        #pragma unroll
        for (int jj=0;jj<4;jj++){
          int ntg = (wave-4)*4 + jj;
          bf16x8 Bc = *(const bf16x8*)&g_wpk[WCF + ((ntg*8+s)*64+lane)*8];
          cc[jj][0] = MFMA(A0, Bc, cc[jj][0]);
          cc[jj][1] = MFMA(A1, Bc, cc[jj][1]);
        }
      }
      #pragma unroll
      for (int jj=0;jj<4;jj++){
        int ntg = (wave-4)*4 + jj;
        float bc = bqkv[4*(ntg*16+n16) + 3];
        #pragma unroll
        for (int mt=0;mt<2;mt++){
          chp[(jj*2+mt)*2+0] = pk2(cc[jj][mt][0]+bc, cc[jj][mt][1]+bc);
          chp[(jj*2+mt)*2+1] = pk2(cc[jj][mt][2]+bc, cc[jj][mt][3]+bc);
        }
      }
    } else {
      // ---- hf=1: dump ch regs -> MCH (Y rows now dead) ----
      #pragma unroll
      for (int jj=0;jj<4;jj++){
        int ntg = (wave-4)*4 + jj;
        int col = ntg*16 + n16;
        #pragma unroll
        for (int mt=0;mt<2;mt++){
          #pragma unroll
          for (int r2=0;r2<2;r2++){
            uint32_t v = chp[(jj*2+mt)*2+r2];
            int row = mt*16 + quad*4 + r2*2;
            sm[MCH + row*MCSTR + col]     = (uint16_t)(v & 0xffffu);
            sm[MCH + (row+1)*MCSTR + col] = (uint16_t)(v >> 16);
          }
        }
      }
    }
    __syncthreads();
  }
  // ---- dump attention output -> MAO (Q/K dead), then W1 GEMM ----
  if (wave < 4){
    int p = lane & 31, half = lane >> 5;
    int cb = wave*32 + half*16;
    #pragma unroll
    for (int hf=0;hf<2;hf++)
      #pragma unroll
      for (int i=0;i<8;i++)
        *(uint32_t*)&sm[MAO + p*MAOSTR + hf*128 + cb + 2*i] = opk[hf][i];
  }
  // h = relu(ch @ W1^T + b1), N=128 (ntg = wave)
  {
    int ntg = wave;
    bf16x8 Bf[8];
    #pragma unroll
    for (int s=0;s<8;s++) Bf[s] = *(const bf16x8*)&g_wpk[W1F + ((ntg*8+s)*64+lane)*8];
    float bs = b1[ntg*16+n16];
    int colB = wave*16;
    #pragma unroll
    for (int mt=0;mt<2;mt++){
      f32x4 a = {0.f,0.f,0.f,0.f};
      #pragma unroll
      for (int s=0;s<8;s++){
        bf16x8 A = *(const bf16x8*)&sm[MCH + (mt*16+n16)*MCSTR + s*32 + quad*8];
        a = MFMA(A, Bf[s], a);
      }
      #pragma unroll
      for (int r=0;r<4;r++){
        int row = mt*16 + quad*4 + r;
        sm[MHS + row*HSTR + colB + n16] = f2bn(fmaxf(a[r]+bs, 0.f));
      }
    }
  }
  __syncthreads();
  // g = sigmoid(h @ W2^T + b2); t = ao*(1+g) -> MCH (ch dead); A-reads shared across jj
  {
    int nt0 = wave*2, nt1 = nt0+1;
    f32x4 g00={0.f,0.f,0.f,0.f}, g01={0.f,0.f,0.f,0.f};
    f32x4 g10={0.f,0.f,0.f,0.f}, g11={0.f,0.f,0.f,0.f};
    #pragma unroll
    for (int s=0;s<4;s++){
      bf16x8 B0 = *(const bf16x8*)&g_wpk[W2F + ((nt0*4+s)*64+lane)*8];
      bf16x8 B1 = *(const bf16x8*)&g_wpk[W2F + ((nt1*4+s)*64+lane)*8];
      bf16x8 A0 = *(const bf16x8*)&sm[MHS + n16*HSTR + s*32 + quad*8];
      bf16x8 A1 = *(const bf16x8*)&sm[MHS + (16+n16)*HSTR + s*32 + quad*8];
      g00 = MFMA(A0,B0,g00); g01 = MFMA(A1,B0,g01);
      g10 = MFMA(A0,B1,g10); g11 = MFMA(A1,B1,g11);
    }
    float bs0 = b2v[nt0*16+n16], bs1 = b2v[nt1*16+n16];
    #pragma unroll
    for (int jj=0;jj<2;jj++){
      int colB = (wave*2+jj)*16;
      float bs = jj ? bs1 : bs0;
      #pragma unroll
      for (int mt=0;mt<2;mt++){
        f32x4 a = jj ? (mt ? g11 : g10) : (mt ? g01 : g00);
        #pragma unroll
        for (int r=0;r<4;r++){
          int row = mt*16 + quad*4 + r;
          float gg = 1.f/(1.f+__expf(-(a[r] + bs)));
          float ao = b2f((uint32_t)sm[MAO + row*MAOSTR + colB + n16]);
          sm[MCH + row*MCSTR + colB + n16] = f2bn(ao*(1.f+gg));
        }
      }
    }
  }
  __syncthreads();
  // out_t = t @ Wp^T + bp -> MAOT transposed [c][pixel] (MAO dead), b64 writes;
  // A-reads shared across jj
  {
    int nt0 = wave*2, nt1 = nt0+1;
    f32x4 p00={0.f,0.f,0.f,0.f}, p01={0.f,0.f,0.f,0.f};
    f32x4 p10={0.f,0.f,0.f,0.f}, p11={0.f,0.f,0.f,0.f};
    #pragma unroll
    for (int s=0;s<8;s++){
      bf16x8 B0 = *(const bf16x8*)&g_wpk[WPF + ((nt0*8+s)*64+lane)*8];
      bf16x8 B1 = *(const bf16x8*)&g_wpk[WPF + ((nt1*8+s)*64+lane)*8];
      bf16x8 A0 = *(const bf16x8*)&sm[MCH + n16*MCSTR + s*32 + quad*8];
      bf16x8 A1 = *(const bf16x8*)&sm[MCH + (16+n16)*MCSTR + s*32 + quad*8];
      p00 = MFMA(A0,B0,p00); p01 = MFMA(A1,B0,p01);
      p10 = MFMA(A0,B1,p10); p11 = MFMA(A1,B1,p11);
    }
    float bs0 = bp[nt0*16+n16], bs1 = bp[nt1*16+n16];
    #pragma unroll
    for (int jj=0;jj<2;jj++){
      int col = (wave*2+jj)*16 + n16;
      float bs = jj ? bs1 : bs0;
      #pragma unroll
      for (int mt=0;mt<2;mt++){
        f32x4 a = jj ? (mt ? p11 : p10) : (mt ? p01 : p00);
        u32x2 pk = { pk2(a[0]+bs, a[1]+bs), pk2(a[2]+bs, a[3]+bs) };
        int row0 = mt*16 + quad*4;
        *(u32x2*)&sm[MAOT + col*MTSTR + row0] = pk;
      }
    }
  }
  __syncthreads();
  // fp32 NCHW write: task=(c, iy, ix4); b64 read of 4 consecutive pixels at fixed c
  #pragma unroll
  for (int i=0;i<4;i++){
    int idx = t + 512*i;                // 2048 tasks
    int ix4 = idx&1, iy = (idx>>1)&3, c = idx>>3;
    int p0 = iy*8 + ix4*4;
    u32x2 pk = *(const u32x2*)&sm[MAOT + c*MTSTR + p0];
    f32x4 stv;
    stv[0] = blo(pk[0]); stv[1] = bhi(pk[0]);
    stv[2] = blo(pk[1]); stv[3] = bhi(pk[1]);
    *(f32x4*)&out[(((bb*256+c)*64) + ty*4+iy)*64 + tx*8 + ix4*4] = stv;
  }
}

extern "C" void kernel_launch(void* const* d_in, const int* in_sizes, int n_in,
                              void* d_out, int out_size, void* d_ws, size_t ws_size,
                              hipStream_t stream){
  (void)in_sizes; (void)n_in; (void)d_ws; (void)ws_size; (void)out_size;
  const float* x    = (const float*)d_in[0];
  const float* Wqkv = (const float*)d_in[1];
  const float* bqkv = (const float*)d_in[2];
  const float* W1   = (const float*)d_in[3];
  const float* b1   = (const float*)d_in[4];
  const float* W2   = (const float*)d_in[5];
  const float* b2   = (const float*)d_in[6];
  const float* Wp   = (const float*)d_in[7];
  const float* bp   = (const float*)d_in[8];
  kprep<<<dim3(1280), dim3(512), 0, stream>>>(x, Wqkv, W1, W2, Wp);
  kattn<<<dim3(1024), dim3(512), 0, stream>>>(bqkv, b1, b2, bp, (float*)d_out);
}

// Round 11
// 173.976 us; speedup vs baseline: 1.0132x; 1.0132x over previous
//
#include <hip/hip_runtime.h>
#include <stdint.h>

// ---------- types ----------
typedef __bf16    bf16x8 __attribute__((ext_vector_type(8)));
typedef float     f32x4  __attribute__((ext_vector_type(4)));
typedef uint32_t  u32x4  __attribute__((ext_vector_type(4)));
typedef uint32_t  u32x2  __attribute__((ext_vector_type(2)));

#define MFMA(a,b,c) __builtin_amdgcn_mfma_f32_16x16x32_bf16((a),(b),(c),0,0,0)

// ---------- persistent device scratch (bf16 internal pipeline) ----------
__device__ __align__(16) uint16_t g_y [8*64*64*256];
__device__ __align__(16) uint16_t g_wpk[393216];

#define WQF 0
#define WKF 65536
#define WVF 131072
#define WCF 196608
#define W1F 262144
#define W2F 294912
#define WPF 327680

static __device__ __forceinline__ float b2f(uint32_t u){ return __builtin_bit_cast(float, u<<16); }
static __device__ __forceinline__ float blo(uint32_t u){ return __builtin_bit_cast(float, u<<16); }
static __device__ __forceinline__ float bhi(uint32_t u){ return __builtin_bit_cast(float, u & 0xffff0000u); }
// native RNE f32->bf16 (same bits as manual RNE round)
static __device__ __forceinline__ uint16_t f2bn(float f){
  return __builtin_bit_cast(uint16_t, (__bf16)f);
}
static __device__ __forceinline__ uint32_t pk2(float x, float y){
  return (uint32_t)f2bn(x) | ((uint32_t)f2bn(y) << 16);
}

// ---------- kernel 0 (fused prep) ----------
// blocks [0,512):   3x3 avgpool, 8 output rows x 32-ch group per block
//                   (1.25x read amplification; LDS 52.5 KB -> 3 blocks/CU)
// blocks [512,1280): weight repack into bf16 B-fragment-major layout
__global__ __launch_bounds__(512) void kprep(const float* __restrict__ x,
    const float* __restrict__ Wqkv, const float* __restrict__ W1,
    const float* __restrict__ W2, const float* __restrict__ Wp){
  int t = threadIdx.x;
  int bid = blockIdx.x;
  if (bid < 512){
    // pool: block = (b:8, hg:8 of 8 rows, cg:8 of 32 ch)
    __shared__ __align__(16) uint16_t sm[10*32*82];   // 52,480 B
    uint32_t* smw = (uint32_t*)sm;
    int b = bid >> 6, rem = bid & 63;
    int hg = rem >> 3, cg = rem & 7;
    int h0 = hg*8, ch = cg*32;
    // zero pad cols 6/7 and 72/73 of each (plane,c) row (320 rows x 41 dwords)
    for (int i=t; i<320; i+=512){
      int base = i*41;
      smw[base+3]  = 0;
      smw[base+36] = 0;
    }
    // OOB planes (only top/bottom hgroups); plane = 32*82 u16 = 1312 dwords
    if (hg==0){
      for (int i=t; i<1312; i+=512) smw[i] = 0;
    }
    if (hg==7){
      for (int i=t; i<1312; i+=512) smw[9*1312 + i] = 0;
    }
    // load 10 input rows x 32 ch x 64 w (fp32 -> bf16)
    #pragma unroll
    for (int i=0;i<10;i++){
      int id = t + 512*i;            // 5120 chunks of 4 fp32
      int w4 = id&15, c = (id>>4)&31, hh = id>>9;
      int gy = h0 - 1 + hh;
      if ((unsigned)gy < 64u){
        f32x4 ld = *(const f32x4*)&x[(((b*256+ch+c)*64+gy)*64) + w4*4];
        int wb = (((hh*32+c)*82 + 8 + w4*4) >> 1);
        smw[wb+0] = pk2(ld[0], ld[1]);
        smw[wb+1] = pk2(ld[2], ld[3]);
      }
    }
    __syncthreads();
    // compute 8 output rows x 32 ch x 64 w with rolling column sums
    int c = t & 31, wsel = (t >> 5) & 1, py = t >> 6;
    int r0 = ((py+0)*32+c)*82, r1 = ((py+1)*32+c)*82, r2 = ((py+2)*32+c)*82;
    int w0 = wsel*32;
    float csp = b2f(sm[r0+w0+7]) + b2f(sm[r1+w0+7]) + b2f(sm[r2+w0+7]);
    float csc = b2f(sm[r0+w0+8]) + b2f(sm[r1+w0+8]) + b2f(sm[r2+w0+8]);
    uint16_t* dst = g_y + ((b*64 + h0 + py)*64)*256 + ch + c;
    for (int j2=0;j2<32;j2++){
      int w = w0 + j2;
      float csn = b2f(sm[r0+w+9]) + b2f(sm[r1+w+9]) + b2f(sm[r2+w+9]);
      float yv = (csp + csc + csn) * (1.0f/9.0f);
      dst[w*256] = f2bn(yv);
      csp = csc; csc = csn;
    }
  } else {
    int idx = (bid - 512)*512 + t;
    int j = idx & 7, lane = (idx>>3)&63;
    int n16 = lane & 15, q4 = lane>>4;
    float v;
    if (idx < 262144){
      int tt = idx >> 16, l = idx & 65535;
      int s = (l>>9)&7, nt = l>>12;
      v = Wqkv[(4*(nt*16+n16) + tt)*256 + s*32 + q4*8 + j];
    } else if (idx < 294912){
      int l = idx - 262144;
      int s = (l>>9)&7, nt = l>>12;
      v = W1[(nt*16+n16)*256 + s*32 + q4*8 + j];
    } else if (idx < 327680){
      int l = idx - 294912;
      int s = (l>>9)&3, nt = l>>11;
      v = W2[(nt*16+n16)*128 + s*32 + q4*8 + j];
    } else {
      int l = idx - 327680;
      int s = (l>>9)&7, nt = l>>12;
      v = Wp[(nt*16+n16)*256 + s*32 + q4*8 + j];
    }
    g_wpk[idx] = f2bn(v);
  }
}

// ---------- kernel 1: fully fused qkv + attention + chans + gate MLP + proj + out ----------
// tile = 4x8 interior (6x10 halo); LDS 73.0 KB -> 2 blocks/CU (4 waves/SIMD)
// EXACT round-9 kernel (best measured: 81.0 us steady-state).
#define YSTR  264        // 60 halo rows
#define HSTR  136        // 16B-aligned rows -> b128 attention reads
#define K2_QS 15840      // Q: 32 x 136
#define K2_KS 20192      // K: 60 x 136
#define K2_VS 28352      // V: 60 x 136  (total 36512 u16 = 73024 B)
#define MCH   0          // 32x264 over dead Y rows
#define MHS   8448       // 32x136 over dead Y rows
#define MAO   15840      // 32x266 attn out, over dead Q/K
#define MAOSTR 266
#define MAOT  15840      // 256x36 transposed proj out, overlays dead MAO after W2
#define MTSTR 36
__global__ __launch_bounds__(512,4) void kattn(const float* __restrict__ bqkv,
    const float* __restrict__ b1, const float* __restrict__ b2v,
    const float* __restrict__ bp, float* __restrict__ out){
  __shared__ __align__(16) uint16_t sm[36512];   // 73.0 KB
  int t = threadIdx.x;
  int lane = t & 63, wave = t >> 6;
  int n16 = lane & 15, quad = lane >> 4;
  int bid = blockIdx.x;
  int bb = bid >> 7, ty = (bid >> 3) & 15, tx = bid & 7;

  uint32_t opk[2][8];    // packed attention output (waves 0-3)
  uint32_t chp[16];      // packed chans GEMM output (waves 4-7)

  int hrow0 = 10*(n16>>3) + (n16&7) + 11;   // interior row for m = n16
  int hrow1 = hrow0 + 20;                   // interior row for m = 16+n16

  // --- load 6x10 y-halo (zero outside image) ---
  #pragma unroll
  for (int i=0;i<4;i++){
    int id = t + 512*i;
    if (id < 1920){
      int hp = id >> 5, c8 = id & 31;
      int py = hp/10, px = hp - py*10;
      int gy = ty*4 + py - 1, gx = tx*8 + px - 1;
      u32x4 ld = {0,0,0,0};
      if ((unsigned)gy<64u && (unsigned)gx<64u)
        ld = *(const u32x4*)&g_y[((bb*64+gy)*64+gx)*256 + c8*8];
      *(u32x4*)&sm[hp*YSTR + c8*8] = ld;
    }
  }
  __syncthreads();

  #pragma unroll
  for (int hf=0; hf<2; hf++){
    // ---- q GEMM: M=32 interior, N=128 (this half) ----
    {
      int ntg = hf*8 + wave;
      bf16x8 Bq[8];
      #pragma unroll
      for (int s=0;s<8;s++) Bq[s] = *(const bf16x8*)&g_wpk[WQF + ((ntg*8+s)*64+lane)*8];
      float bq = bqkv[4*(ntg*16+n16) + 0];
      int colB = wave*16;
      #pragma unroll
      for (int mt=0; mt<2; mt++){
        f32x4 a = {0.f,0.f,0.f,0.f};
        int hrow = mt ? hrow1 : hrow0;
        #pragma unroll
        for (int s=0;s<8;s++){
          bf16x8 A = *(const bf16x8*)&sm[hrow*YSTR + s*32 + quad*8];
          a = MFMA(A, Bq[s], a);
        }
        #pragma unroll
        for (int r=0;r<4;r++){
          int row = mt*16 + quad*4 + r;
          sm[K2_QS + row*HSTR + colB + n16] = f2bn(a[r] + bq);
        }
      }
    }
    // (no barrier: Q and KV write disjoint LDS, read only Y — proven r8)
    // ---- k & v GEMM (shared A-frags): M=64 (rows >= 60 discarded), N=128 ----
    {
      int ntg = hf*8 + wave;
      bf16x8 Bk[8], Bv[8];
      #pragma unroll
      for (int s=0;s<8;s++){
        Bk[s] = *(const bf16x8*)&g_wpk[WKF + ((ntg*8+s)*64+lane)*8];
        Bv[s] = *(const bf16x8*)&g_wpk[WVF + ((ntg*8+s)*64+lane)*8];
      }
      float bk = bqkv[4*(ntg*16+n16) + 1];
      float bv = bqkv[4*(ntg*16+n16) + 2];
      int colB = wave*16;
      #pragma unroll
      for (int mt=0; mt<4; mt++){
        f32x4 ak = {0.f,0.f,0.f,0.f}, av = {0.f,0.f,0.f,0.f};
        int m = mt*16 + n16;
        int mr = (m < 60) ? m : 59;
        #pragma unroll
        for (int s=0;s<8;s++){
          bf16x8 A = *(const bf16x8*)&sm[mr*YSTR + s*32 + quad*8];
          ak = MFMA(A, Bk[s], ak);
          av = MFMA(A, Bv[s], av);
        }
        #pragma unroll
        for (int r=0;r<4;r++){
          int row = mt*16 + quad*4 + r;
          if (row < 60){
            int py = row/10, px = row - py*10;
            int gy = ty*4 + py - 1, gx = tx*8 + px - 1;
            bool ok = ((unsigned)gy<64u) && ((unsigned)gx<64u);
            sm[K2_KS + row*HSTR + colB + n16] = ok ? f2bn(ak[r] + bk) : (uint16_t)0;
            sm[K2_VS + row*HSTR + colB + n16] = ok ? f2bn(av[r] + bv) : (uint16_t)0;
          }
        }
      }
    }
    __syncthreads();
    if (wave < 4){
      // ---- attention: thread = (pixel, head, ch-half); cross-half dot via shfl_xor ----
      int p = lane & 31, half = lane >> 5;
      int cb = wave*32 + half*16;
      const uint16_t* qp = &sm[K2_QS + p*HSTR + cb];
      u32x4 qa = *(const u32x4*)qp;
      u32x4 qb = *(const u32x4*)(qp+8);
      float qv[16];
      #pragma unroll
      for (int i=0;i<4;i++){
        qv[2*i]    = blo(qa[i]); qv[2*i+1]   = bhi(qa[i]);
        qv[8+2*i]  = blo(qb[i]); qv[8+2*i+1] = bhi(qb[i]);
      }
      int hb = 10*(p>>3) + (p&7) + 11;
      const int off[9] = {-11,-10,-9,-1,0,1,9,10,11};
      float sc[9];
      #pragma unroll
      for (int nb=0;nb<9;nb++){
        const uint16_t* kp = &sm[K2_KS + (hb+off[nb])*HSTR + cb];
        u32x4 ka = *(const u32x4*)kp;
        u32x4 kb = *(const u32x4*)(kp+8);
        float s = 0.f;
        #pragma unroll
        for (int i=0;i<4;i++){
          s += qv[2*i]*blo(ka[i])   + qv[2*i+1]*bhi(ka[i]);
          s += qv[8+2*i]*blo(kb[i]) + qv[8+2*i+1]*bhi(kb[i]);
        }
        s += __shfl_xor(s, 32);            // combine the two 16-ch halves of the head
        sc[nb] = s * 0.17677669529663687f;
      }
      float mx = sc[0];
      #pragma unroll
      for (int nb=1;nb<9;nb++) mx = fmaxf(mx, sc[nb]);
      float l = 0.f;
      #pragma unroll
      for (int nb=0;nb<9;nb++){ sc[nb] = __expf(sc[nb]-mx); l += sc[nb]; }
      float inv = 1.f / l;
      float o[16];
      #pragma unroll
      for (int i=0;i<16;i++) o[i]=0.f;
      #pragma unroll
      for (int nb=0;nb<9;nb++){
        float wgt = sc[nb]*inv;
        const uint16_t* vp = &sm[K2_VS + (hb+off[nb])*HSTR + cb];
        u32x4 va = *(const u32x4*)vp;
        u32x4 vb = *(const u32x4*)(vp+8);
        #pragma unroll
        for (int i=0;i<4;i++){
          o[2*i]    += wgt*blo(va[i]); o[2*i+1]   += wgt*bhi(va[i]);
          o[8+2*i]  += wgt*blo(vb[i]); o[8+2*i+1] += wgt*bhi(vb[i]);
        }
      }
      #pragma unroll
      for (int i=0;i<8;i++) opk[hf][i] = pk2(o[2*i], o[2*i+1]);
    } else if (hf == 0){
      // ---- chans GEMM (concurrent with attn0): A-reads hoisted across jj ----
      f32x4 cc[4][2];
      #pragma unroll
      for (int jj=0;jj<4;jj++){
        cc[jj][0] = f32x4{0.f,0.f,0.f,0.f};
        cc[jj][1] = f32x4{0.f,0.f,0.f,0.f};
      }
      #pragma unroll
      for (int s=0;s<8;s++){
        bf16x8 A0 = *(const bf16x8*)&sm[hrow0*YSTR + s*32 + quad*8];
        bf16x8 A1 = *(const bf16x8*)&sm[hrow1*YSTR + s*32 + quad*8];
        #pragma unroll
        for (int jj=0;jj<4;jj++){
          int ntg = (wave-4)*4 + jj;
          bf16x8 Bc = *(const bf16x8*)&g_wpk[WCF + ((ntg*8+s)*64+lane)*8];
          cc[jj][0] = MFMA(A0, Bc, cc[jj][0]);
          cc[jj][1] = MFMA(A1, Bc, cc[jj][1]);
        }
      }
      #pragma unroll
      for (int jj=0;jj<4;jj++){
        int ntg = (wave-4)*4 + jj;
        float bc = bqkv[4*(ntg*16+n16) + 3];
        #pragma unroll
        for (int mt=0;mt<2;mt++){
          chp[(jj*2+mt)*2+0] = pk2(cc[jj][mt][0]+bc, cc[jj][mt][1]+bc);
          chp[(jj*2+mt)*2+1] = pk2(cc[jj][mt][2]+bc, cc[jj][mt][3]+bc);
        }
      }
    } else {
      // ---- hf=1: dump ch regs -> MCH (Y rows now dead) ----
      #pragma unroll
      for (int jj=0;jj<4;jj++){
        int ntg = (wave-4)*4 + jj;
        int col = ntg*16 + n16;
        #pragma unroll
        for (int mt=0;mt<2;mt++){
          #pragma unroll
          for (int r2=0;r2<2;r2++){
            uint32_t v = chp[(jj*2+mt)*2+r2];
            int row = mt*16 + quad*4 + r2*2;
            sm[MCH + row*264 + col]     = (uint16_t)(v & 0xffffu);
            sm[MCH + (row+1)*264 + col] = (uint16_t)(v >> 16);
          }
        }
      }
    }
    __syncthreads();
  }
  // ---- dump attention output -> MAO (Q/K dead), then W1 GEMM ----
  if (wave < 4){
    int p = lane & 31, half = lane >> 5;
    int cb = wave*32 + half*16;
    #pragma unroll
    for (int hf=0;hf<2;hf++)
      #pragma unroll
      for (int i=0;i<8;i++)
        *(uint32_t*)&sm[MAO + p*MAOSTR + hf*128 + cb + 2*i] = opk[hf][i];
  }
  // h = relu(ch @ W1^T + b1), N=128 (ntg = wave)
  {
    int ntg = wave;
    bf16x8 Bf[8];
    #pragma unroll
    for (int s=0;s<8;s++) Bf[s] = *(const bf16x8*)&g_wpk[W1F + ((ntg*8+s)*64+lane)*8];
    float bs = b1[ntg*16+n16];
    int colB = wave*16;
    #pragma unroll
    for (int mt=0;mt<2;mt++){
      f32x4 a = {0.f,0.f,0.f,0.f};
      #pragma unroll
      for (int s=0;s<8;s++){
        bf16x8 A = *(const bf16x8*)&sm[MCH + (mt*16+n16)*264 + s*32 + quad*8];
        a = MFMA(A, Bf[s], a);
      }
      #pragma unroll
      for (int r=0;r<4;r++){
        int row = mt*16 + quad*4 + r;
        sm[MHS + row*HSTR + colB + n16] = f2bn(fmaxf(a[r]+bs, 0.f));
      }
    }
  }
  __syncthreads();
  // g = sigmoid(h @ W2^T + b2); t = ao*(1+g) -> MCH (ch dead); A-reads shared across jj
  {
    int nt0 = wave*2, nt1 = nt0+1;
    f32x4 g00={0.f,0.f,0.f,0.f}, g01={0.f,0.f,0.f,0.f};
    f32x4 g10={0.f,0.f,0.f,0.f}, g11={0.f,0.f,0.f,0.f};
    #pragma unroll
    for (int s=0;s<4;s++){
      bf16x8 B0 = *(const bf16x8*)&g_wpk[W2F + ((nt0*4+s)*64+lane)*8];
      bf16x8 B1 = *(const bf16x8*)&g_wpk[W2F + ((nt1*4+s)*64+lane)*8];
      bf16x8 A0 = *(const bf16x8*)&sm[MHS + n16*HSTR + s*32 + quad*8];
      bf16x8 A1 = *(const bf16x8*)&sm[MHS + (16+n16)*HSTR + s*32 + quad*8];
      g00 = MFMA(A0,B0,g00); g01 = MFMA(A1,B0,g01);
      g10 = MFMA(A0,B1,g10); g11 = MFMA(A1,B1,g11);
    }
    float bs0 = b2v[nt0*16+n16], bs1 = b2v[nt1*16+n16];
    #pragma unroll
    for (int jj=0;jj<2;jj++){
      int colB = (wave*2+jj)*16;
      float bs = jj ? bs1 : bs0;
      #pragma unroll
      for (int mt=0;mt<2;mt++){
        f32x4 a = jj ? (mt ? g11 : g10) : (mt ? g01 : g00);
        #pragma unroll
        for (int r=0;r<4;r++){
          int row = mt*16 + quad*4 + r;
          float gg = 1.f/(1.f+__expf(-(a[r] + bs)));
          float ao = b2f((uint32_t)sm[MAO + row*MAOSTR + colB + n16]);
          sm[MCH + row*264 + colB + n16] = f2bn(ao*(1.f+gg));
        }
      }
    }
  }
  __syncthreads();
  // out_t = t @ Wp^T + bp -> MAOT transposed [c][pixel] (MAO dead), b64 writes;
  // A-reads shared across jj
  {
    int nt0 = wave*2, nt1 = nt0+1;
    f32x4 p00={0.f,0.f,0.f,0.f}, p01={0.f,0.f,0.f,0.f};
    f32x4 p10={0.f,0.f,0.f,0.f}, p11={0.f,0.f,0.f,0.f};
    #pragma unroll
    for (int s=0;s<8;s++){
      bf16x8 B0 = *(const bf16x8*)&g_wpk[WPF + ((nt0*8+s)*64+lane)*8];
      bf16x8 B1 = *(const bf16x8*)&g_wpk[WPF + ((nt1*8+s)*64+lane)*8];
      bf16x8 A0 = *(const bf16x8*)&sm[MCH + n16*264 + s*32 + quad*8];
      bf16x8 A1 = *(const bf16x8*)&sm[MCH + (16+n16)*264 + s*32 + quad*8];
      p00 = MFMA(A0,B0,p00); p01 = MFMA(A1,B0,p01);
      p10 = MFMA(A0,B1,p10); p11 = MFMA(A1,B1,p11);
    }
    float bs0 = bp[nt0*16+n16], bs1 = bp[nt1*16+n16];
    #pragma unroll
    for (int jj=0;jj<2;jj++){
      int col = (wave*2+jj)*16 + n16;
      float bs = jj ? bs1 : bs0;
      #pragma unroll
      for (int mt=0;mt<2;mt++){
        f32x4 a = jj ? (mt ? p11 : p10) : (mt ? p01 : p00);
        u32x2 pk = { pk2(a[0]+bs, a[1]+bs), pk2(a[2]+bs, a[3]+bs) };
        int row0 = mt*16 + quad*4;
        *(u32x2*)&sm[MAOT + col*MTSTR + row0] = pk;
      }
    }
  }
  __syncthreads();
  // fp32 NCHW write: task=(c, iy, ix4); b64 read of 4 consecutive pixels at fixed c
  #pragma unroll
  for (int i=0;i<4;i++){
    int idx = t + 512*i;                // 2048 tasks
    int ix4 = idx&1, iy = (idx>>1)&3, c = idx>>3;
    int p0 = iy*8 + ix4*4;
    u32x2 pk = *(const u32x2*)&sm[MAOT + c*MTSTR + p0];
    f32x4 stv;
    stv[0] = blo(pk[0]); stv[1] = bhi(pk[0]);
    stv[2] = blo(pk[1]); stv[3] = bhi(pk[1]);
    *(f32x4*)&out[(((bb*256+c)*64) + ty*4+iy)*64 + tx*8 + ix4*4] = stv;
  }
}

extern "C" void kernel_launch(void* const* d_in, const int* in_sizes, int n_in,
                              void* d_out, int out_size, void* d_ws, size_t ws_size,
                              hipStream_t stream){
  (void)in_sizes; (void)n_in; (void)d_ws; (void)ws_size; (void)out_size;
  const float* x    = (const float*)d_in[0];
  const float* Wqkv = (const float*)d_in[1];
  const float* bqkv = (const float*)d_in[2];
  const float* W1   = (const float*)d_in[3];
  const float* b1   = (const float*)d_in[4];
  const float* W2   = (const float*)d_in[5];
  const float* b2   = (const float*)d_in[6];
  const float* Wp   = (const float*)d_in[7];
  const float* bp   = (const float*)d_in[8];
  kprep<<<dim3(1280), dim3(512), 0, stream>>>(x, Wqkv, W1, W2, Wp);
  kattn<<<dim3(1024), dim3(512), 0, stream>>>(bqkv, b1, b2, bp, (float*)d_out);
}